// Round 4
// baseline (634.267 us; speedup 1.0000x reference)
//
#include <hip/hip_runtime.h>
#include <math.h>

#define N_NODES 100000
#define NNZ_E   3200000
#define NFEAT   512
#define NHID    256
#define NCLASS  41
#define NC_PAD  48     // w2t padded rows
#define P_STRIDE 64    // p row stride in bytes (fp8)

typedef __attribute__((ext_vector_type(8))) short   short8;   // 8 bf16 (4 VGPRs)
typedef __attribute__((ext_vector_type(8))) unsigned short ushort8;
typedef __attribute__((ext_vector_type(4))) float   f32x4;
typedef __attribute__((ext_vector_type(2))) float   f32x2;

// ---- bf16 helpers ----
__device__ __forceinline__ unsigned short f2bf(float f) {
    unsigned u = __builtin_bit_cast(unsigned, f);
    unsigned r = u + 0x7fffu + ((u >> 16) & 1u);   // RNE
    return (unsigned short)(r >> 16);
}
// ---- fp8 e4m3 helpers (OCP, native gfx950 cvt) ----
__device__ __forceinline__ unsigned char f2fp8(float f) {
    return (unsigned char)(__builtin_amdgcn_cvt_pk_fp8_f32(f, 0.f, 0, false) & 0xff);
}

// ---------------------------------------------------------------------------
// K0: w1t = bf16(w1^T) [256][512];  w2t = bf16(w2^T zero-padded) [48][256]
// ---------------------------------------------------------------------------
__global__ void prep_w_kernel(const float* __restrict__ w1, const float* __restrict__ w2,
                              unsigned short* __restrict__ w1t, unsigned short* __restrict__ w2t) {
    int tid = blockIdx.x * 256 + threadIdx.x;
    if (tid < NHID * NFEAT) {
        int n = tid >> 9, k = tid & 511;
        w1t[tid] = f2bf(w1[k * NHID + n]);
    }
    int t2 = tid - NHID * NFEAT;
    if (t2 >= 0 && t2 < NC_PAD * NHID) {
        int n = t2 >> 8, k = t2 & 255;
        w2t[t2] = (n < NCLASS) ? f2bf(w2[k * NCLASS + n]) : (unsigned short)0;
    }
}

// ---------------------------------------------------------------------------
// K1: CSR row_ptr from sorted adj_rows (lower_bound per row)
// ---------------------------------------------------------------------------
__global__ void rowptr_kernel(const int* __restrict__ rows, int* __restrict__ row_ptr) {
    int r = blockIdx.x * 256 + threadIdx.x;
    if (r > N_NODES) return;
    int lo = 0, hi = NNZ_E;
    while (lo < hi) {
        int mid = (lo + hi) >> 1;
        if (rows[mid] < r) lo = mid + 1; else hi = mid;
    }
    row_ptr[r] = lo;
}

// ---------------------------------------------------------------------------
// K2: XW = x @ w1  (bf16 MFMA, fp32 acc) -> xw fp8 [N,256]
// NO LDS, NO barriers: A-frags loaded direct from global (fp32->bf16 in reg,
// block's A slice is L1-resident for the 4 waves); B-frags direct from
// global (w1t is 256 KB, L2-resident, same addrs for every block).
// Each wave: 64 rows x 64 cols as 4x4 of 16x16x32 MFMA tiles.
// ---------------------------------------------------------------------------
__global__ __launch_bounds__(256) void gemm1_kernel(const float* __restrict__ x,
                                                    const unsigned short* __restrict__ w1t,
                                                    unsigned char* __restrict__ xw) {
    const int rb   = blockIdx.x * 64;
    const int wave = threadIdx.x >> 6;
    const int lane = threadIdx.x & 63;
    const int l15  = lane & 15;
    const int quad = lane >> 4;

    f32x4 acc[4][4] = {};

    const float* arow_ptr[4];
#pragma unroll
    for (int mt = 0; mt < 4; mt++) {
        int r = rb + mt * 16 + l15;
        if (r >= N_NODES) r = N_NODES - 1;
        arow_ptr[mt] = x + (long)r * NFEAT + quad * 8;
    }
    const unsigned short* brow = w1t + (long)(wave * 64 + l15) * NFEAT + quad * 8;

    for (int kc = 0; kc < NFEAT; kc += 32) {
        short8 a[4];
#pragma unroll
        for (int mt = 0; mt < 4; mt++) {
            float4 f0 = *(const float4*)(arow_ptr[mt] + kc);
            float4 f1 = *(const float4*)(arow_ptr[mt] + kc + 4);
            ushort8 v;
            v[0] = f2bf(f0.x); v[1] = f2bf(f0.y); v[2] = f2bf(f0.z); v[3] = f2bf(f0.w);
            v[4] = f2bf(f1.x); v[5] = f2bf(f1.y); v[6] = f2bf(f1.z); v[7] = f2bf(f1.w);
            a[mt] = __builtin_bit_cast(short8, v);
        }
#pragma unroll
        for (int nt = 0; nt < 4; nt++) {
            short8 b = *(const short8*)(brow + (long)nt * 16 * NFEAT + kc);
#pragma unroll
            for (int mt = 0; mt < 4; mt++)
                acc[mt][nt] = __builtin_amdgcn_mfma_f32_16x16x32_bf16(a[mt], b, acc[mt][nt], 0, 0, 0);
        }
    }

    // epilogue: C/D layout col=lane&15, row=quad*4+reg
#pragma unroll
    for (int mt = 0; mt < 4; mt++) {
#pragma unroll
        for (int nt = 0; nt < 4; nt++) {
            int col = wave * 64 + nt * 16 + l15;
#pragma unroll
            for (int r = 0; r < 4; r++) {
                int row = rb + mt * 16 + quad * 4 + r;
                if (row < N_NODES)
                    xw[(long)row * NHID + col] = f2fp8(acc[mt][nt][r]);
            }
        }
    }
}

// ---------------------------------------------------------------------------
// K3: h = relu(spmm(A, xw) + b1) -> bf16 [N,256].  One wave per row.
// xw is fp8: lane covers cols 4*lane..4*lane+3, one uint gather per edge.
// ---------------------------------------------------------------------------
__global__ __launch_bounds__(256) void spmm1_kernel(const unsigned char* __restrict__ xw,
                                                    const int* __restrict__ row_ptr,
                                                    const int* __restrict__ cols,
                                                    const float* __restrict__ vals,
                                                    const float* __restrict__ b1,
                                                    unsigned short* __restrict__ h) {
    int row = blockIdx.x * 4 + (threadIdx.x >> 6);
    if (row >= N_NODES) return;
    int lane = threadIdx.x & 63;
    int e0 = row_ptr[row], e1 = row_ptr[row + 1];

    float a0 = 0.f, a1 = 0.f, a2 = 0.f, a3 = 0.f;
    for (int base = e0; base < e1; base += 64) {
        int   myc = 0;
        float myv = 0.f;
        int idx = base + lane;
        if (idx < e1) { myc = cols[idx]; myv = vals[idx]; }
        int cnt = e1 - base; if (cnt > 64) cnt = 64;
        int j = 0;
        for (; j + 8 <= cnt; j += 8) {
            int c[8]; float v[8];
#pragma unroll
            for (int u = 0; u < 8; u++) { c[u] = __shfl(myc, j + u); v[u] = __shfl(myv, j + u); }
            unsigned q[8];
#pragma unroll
            for (int u = 0; u < 8; u++) q[u] = *(const unsigned*)(xw + (long)c[u] * NHID + lane * 4);
#pragma unroll
            for (int u = 0; u < 8; u++) {
                f32x2 lo = __builtin_amdgcn_cvt_pk_f32_fp8((int)q[u], false);
                f32x2 hi = __builtin_amdgcn_cvt_pk_f32_fp8((int)q[u], true);
                a0 += v[u] * lo[0];
                a1 += v[u] * lo[1];
                a2 += v[u] * hi[0];
                a3 += v[u] * hi[1];
            }
        }
        for (; j < cnt; j++) {
            int   c = __shfl(myc, j);
            float v = __shfl(myv, j);
            unsigned q = *(const unsigned*)(xw + (long)c * NHID + lane * 4);
            f32x2 lo = __builtin_amdgcn_cvt_pk_f32_fp8((int)q, false);
            f32x2 hi = __builtin_amdgcn_cvt_pk_f32_fp8((int)q, true);
            a0 += v * lo[0];
            a1 += v * lo[1];
            a2 += v * hi[0];
            a3 += v * hi[1];
        }
    }
    float4 bv = *(const float4*)(b1 + lane * 4);
    a0 = fmaxf(a0 + bv.x, 0.f);
    a1 = fmaxf(a1 + bv.y, 0.f);
    a2 = fmaxf(a2 + bv.z, 0.f);
    a3 = fmaxf(a3 + bv.w, 0.f);
    uint2 o;
    o.x = (unsigned)f2bf(a0) | ((unsigned)f2bf(a1) << 16);
    o.y = (unsigned)f2bf(a2) | ((unsigned)f2bf(a3) << 16);
    *(uint2*)(h + (long)row * NHID + lane * 4) = o;
}

// ---------------------------------------------------------------------------
// K4: p = h @ w2  (bf16 MFMA) -> fp8 [N, P_STRIDE=64] (cols 0..47 written)
// ---------------------------------------------------------------------------
__global__ __launch_bounds__(256) void gemm2_kernel(const unsigned short* __restrict__ h,
                                                    const unsigned short* __restrict__ w2t,
                                                    unsigned char* __restrict__ p) {
    int rt = blockIdx.x * 4 + (threadIdx.x >> 6);
    int row0 = rt * 16;
    if (row0 >= N_NODES) return;
    int lane = threadIdx.x & 63;
    int l15 = lane & 15, quad = lane >> 4;

    int arow = row0 + l15; if (arow >= N_NODES) arow = N_NODES - 1;
    f32x4 acc[3] = {};
#pragma unroll
    for (int kc = 0; kc < NHID; kc += 32) {
        short8 a = *(const short8*)(h + (long)arow * NHID + kc + quad * 8);
#pragma unroll
        for (int nt = 0; nt < 3; nt++) {
            short8 b = *(const short8*)(w2t + (long)(nt * 16 + l15) * NHID + kc + quad * 8);
            acc[nt] = __builtin_amdgcn_mfma_f32_16x16x32_bf16(a, b, acc[nt], 0, 0, 0);
        }
    }
#pragma unroll
    for (int nt = 0; nt < 3; nt++) {
        int col = nt * 16 + l15;
#pragma unroll
        for (int r = 0; r < 4; r++) {
            int row = row0 + quad * 4 + r;
            if (row < N_NODES)
                p[(long)row * P_STRIDE + col] = f2fp8(acc[nt][r]);
        }
    }
}

// ---------------------------------------------------------------------------
// K5: out = log_softmax(spmm(A, p) + b2).  One wave per row.
// p is fp8, 64 B rows. e = lane>>5 (edge of pair), t = lane&31;
// t<12 loads uint = cols {4t..4t+3}. 2 edges/j-step, unroll 4.
// ---------------------------------------------------------------------------
__global__ __launch_bounds__(256) void spmm2_kernel(const unsigned char* __restrict__ p,
                                                    const int* __restrict__ row_ptr,
                                                    const int* __restrict__ cols,
                                                    const float* __restrict__ vals,
                                                    const float* __restrict__ b2,
                                                    float* __restrict__ out) {
    int row = blockIdx.x * 4 + (threadIdx.x >> 6);
    if (row >= N_NODES) return;
    int lane = threadIdx.x & 63;
    int e = lane >> 5;
    int t = lane & 31;
    int e0 = row_ptr[row], e1 = row_ptr[row + 1];

    float a0 = 0.f, a1 = 0.f, a2 = 0.f, a3 = 0.f;
    for (int base = e0; base < e1; base += 64) {
        int   myc = 0;
        float myv = 0.f;
        int idx = base + lane;
        if (idx < e1) { myc = cols[idx]; myv = vals[idx]; }
        int cnt = e1 - base; if (cnt > 64) cnt = 64;
        int j = 0;
        for (; j + 8 <= cnt; j += 8) {
            int c[4]; float v[4];
#pragma unroll
            for (int u = 0; u < 4; u++) {
                c[u] = __shfl(myc, j + 2 * u + e);
                v[u] = __shfl(myv, j + 2 * u + e);
            }
            unsigned q[4];
#pragma unroll
            for (int u = 0; u < 4; u++)
                q[u] = (t < 12) ? *(const unsigned*)(p + (long)c[u] * P_STRIDE + 4 * t) : 0u;
#pragma unroll
            for (int u = 0; u < 4; u++) {
                f32x2 lo = __builtin_amdgcn_cvt_pk_f32_fp8((int)q[u], false);
                f32x2 hi = __builtin_amdgcn_cvt_pk_f32_fp8((int)q[u], true);
                a0 += v[u] * lo[0];
                a1 += v[u] * lo[1];
                a2 += v[u] * hi[0];
                a3 += v[u] * hi[1];
            }
        }
        for (; j < cnt; j += 2) {
            int jj = j + e;
            int jc = jj < cnt ? jj : cnt - 1;       // uniform-exec tail
            int   c = __shfl(myc, jc);
            float v = __shfl(myv, jc);
            if (jj >= cnt) v = 0.f;
            unsigned q = (t < 12) ? *(const unsigned*)(p + (long)c * P_STRIDE + 4 * t) : 0u;
            f32x2 lo = __builtin_amdgcn_cvt_pk_f32_fp8((int)q, false);
            f32x2 hi = __builtin_amdgcn_cvt_pk_f32_fp8((int)q, true);
            a0 += v * lo[0];
            a1 += v * lo[1];
            a2 += v * hi[0];
            a3 += v * hi[1];
        }
    }
    // fold the two edge-halves
    a0 += __shfl_xor(a0, 32);
    a1 += __shfl_xor(a1, 32);
    a2 += __shfl_xor(a2, 32);
    a3 += __shfl_xor(a3, 32);

    int c0 = 4 * t, c1 = 4 * t + 1, c2 = 4 * t + 2, c3 = 4 * t + 3;
    float l0 = (c0 < NCLASS) ? a0 + b2[c0] : -__builtin_inff();
    float l1 = (c1 < NCLASS) ? a1 + b2[c1] : -__builtin_inff();
    float l2 = (c2 < NCLASS) ? a2 + b2[c2] : -__builtin_inff();
    float l3 = (c3 < NCLASS) ? a3 + b2[c3] : -__builtin_inff();
    float m = fmaxf(fmaxf(l0, l1), fmaxf(l2, l3));
#pragma unroll
    for (int s = 16; s; s >>= 1) m = fmaxf(m, __shfl_xor(m, s));
    float esum = ((c0 < NCLASS) ? __expf(l0 - m) : 0.f)
               + ((c1 < NCLASS) ? __expf(l1 - m) : 0.f)
               + ((c2 < NCLASS) ? __expf(l2 - m) : 0.f)
               + ((c3 < NCLASS) ? __expf(l3 - m) : 0.f);
#pragma unroll
    for (int s = 16; s; s >>= 1) esum += __shfl_xor(esum, s);
    float lse = m + __logf(esum);
    if (e == 0) {
        long ob = (long)row * NCLASS;
        if (c0 < NCLASS) out[ob + c0] = l0 - lse;
        if (c1 < NCLASS) out[ob + c1] = l1 - lse;
        if (c2 < NCLASS) out[ob + c2] = l2 - lse;
        if (c3 < NCLASS) out[ob + c3] = l3 - lse;
    }
}

// ---------------------------------------------------------------------------
extern "C" void kernel_launch(void* const* d_in, const int* in_sizes, int n_in,
                              void* d_out, int out_size, void* d_ws, size_t ws_size,
                              hipStream_t stream) {
    const float* x        = (const float*)d_in[0];
    const int*   adj_rows = (const int*)  d_in[1];
    const int*   adj_cols = (const int*)  d_in[2];
    const float* adj_vals = (const float*)d_in[3];
    const float* w1       = (const float*)d_in[4];
    const float* b1       = (const float*)d_in[5];
    const float* w2       = (const float*)d_in[6];
    const float* b2       = (const float*)d_in[7];
    float* out = (float*)d_out;

    char* ws = (char*)d_ws;
    unsigned short* w1t     = (unsigned short*)(ws);                       // 0.25 MB
    unsigned short* w2t     = (unsigned short*)(ws + 0x40000);             // 24 KB
    int*            row_ptr = (int*)           (ws + 0x46000);             // 0.4 MB
    unsigned char*  xw      = (unsigned char*) (ws + 0xA8000);             // 25.6 MB fp8 [N,256]
    unsigned short* hbuf    = (unsigned short*)(ws + 0xA8000 + 25600000L); // 51.2 MB bf16 [N,256]
    unsigned char*  p       = (unsigned char*) (ws + 0xA8000);             // 6.4 MB fp8 [N,64], aliases xw

    prep_w_kernel<<<(NHID * NFEAT + NC_PAD * NHID + 255) / 256, 256, 0, stream>>>(w1, w2, w1t, w2t);
    rowptr_kernel<<<(N_NODES + 1 + 255) / 256, 256, 0, stream>>>(adj_rows, row_ptr);
    gemm1_kernel<<<(N_NODES + 63) / 64, 256, 0, stream>>>(x, w1t, xw);
    spmm1_kernel<<<(N_NODES + 3) / 4, 256, 0, stream>>>(xw, row_ptr, adj_cols, adj_vals, b1, hbuf);
    gemm2_kernel<<<((N_NODES + 15) / 16 + 3) / 4, 256, 0, stream>>>(hbuf, w2t, p);
    spmm2_kernel<<<(N_NODES + 3) / 4, 256, 0, stream>>>(p, row_ptr, adj_cols, adj_vals, b2, out);
}

// Round 5
// 569.985 us; speedup vs baseline: 1.1128x; 1.1128x over previous
//
#include <hip/hip_runtime.h>
#include <math.h>

#define N_NODES 100000
#define NNZ_E   3200000
#define NFEAT   512
#define NHID    256
#define NCLASS  41
#define NC_PAD  48     // w2t padded rows
#define P_STRIDE 64    // p row stride in bytes (fp8)

typedef __attribute__((ext_vector_type(8))) short   short8;   // 8 bf16 (4 VGPRs)
typedef __attribute__((ext_vector_type(8))) unsigned short ushort8;
typedef __attribute__((ext_vector_type(4))) float   f32x4;
typedef __attribute__((ext_vector_type(2))) float   f32x2;

typedef __attribute__((address_space(1))) const unsigned int gu32;
typedef __attribute__((address_space(3))) unsigned int lu32;

// ---- bf16 helpers ----
__device__ __forceinline__ unsigned short f2bf(float f) {
    unsigned u = __builtin_bit_cast(unsigned, f);
    unsigned r = u + 0x7fffu + ((u >> 16) & 1u);   // RNE
    return (unsigned short)(r >> 16);
}
// ---- fp8 e4m3 helpers (OCP, native gfx950 cvt) ----
__device__ __forceinline__ unsigned char f2fp8(float f) {
    return (unsigned char)(__builtin_amdgcn_cvt_pk_fp8_f32(f, 0.f, 0, false) & 0xff);
}

// ---------------------------------------------------------------------------
// K0a: x (fp32, 205 MB) -> x_q (fp8, 51.2 MB). Pure streaming, 16 elems/thread.
// ---------------------------------------------------------------------------
__global__ __launch_bounds__(256) void prep_x_kernel(const float* __restrict__ x,
                                                     unsigned char* __restrict__ xq) {
    long i = (long)(blockIdx.x * 256 + threadIdx.x) * 16;
    float4 f0 = *(const float4*)(x + i);
    float4 f1 = *(const float4*)(x + i + 4);
    float4 f2 = *(const float4*)(x + i + 8);
    float4 f3 = *(const float4*)(x + i + 12);
    uint4 o;
    o.x = (unsigned)__builtin_amdgcn_cvt_pk_fp8_f32(f0.x, f0.y, 0, false);
    o.x = (unsigned)__builtin_amdgcn_cvt_pk_fp8_f32(f0.z, f0.w, (int)o.x, true);
    o.y = (unsigned)__builtin_amdgcn_cvt_pk_fp8_f32(f1.x, f1.y, 0, false);
    o.y = (unsigned)__builtin_amdgcn_cvt_pk_fp8_f32(f1.z, f1.w, (int)o.y, true);
    o.z = (unsigned)__builtin_amdgcn_cvt_pk_fp8_f32(f2.x, f2.y, 0, false);
    o.z = (unsigned)__builtin_amdgcn_cvt_pk_fp8_f32(f2.z, f2.w, (int)o.z, true);
    o.w = (unsigned)__builtin_amdgcn_cvt_pk_fp8_f32(f3.x, f3.y, 0, false);
    o.w = (unsigned)__builtin_amdgcn_cvt_pk_fp8_f32(f3.z, f3.w, (int)o.w, true);
    *(uint4*)(xq + i) = o;
}

// ---------------------------------------------------------------------------
// K0b: w1q = fp8(w1^T) [256][512];  w2t = bf16(w2^T zero-padded) [48][256]
// ---------------------------------------------------------------------------
__global__ void prep_w_kernel(const float* __restrict__ w1, const float* __restrict__ w2,
                              unsigned char* __restrict__ w1q, unsigned short* __restrict__ w2t) {
    int tid = blockIdx.x * 256 + threadIdx.x;
    if (tid < NHID * NFEAT) {
        int n = tid >> 9, k = tid & 511;
        w1q[tid] = f2fp8(w1[k * NHID + n]);
    }
    int t2 = tid - NHID * NFEAT;
    if (t2 >= 0 && t2 < NC_PAD * NHID) {
        int n = t2 >> 8, k = t2 & 255;
        w2t[t2] = (n < NCLASS) ? f2bf(w2[k * NCLASS + n]) : (unsigned short)0;
    }
}

// ---------------------------------------------------------------------------
// K1: CSR row_ptr from sorted adj_rows (lower_bound per row)
// ---------------------------------------------------------------------------
__global__ void rowptr_kernel(const int* __restrict__ rows, int* __restrict__ row_ptr) {
    int r = blockIdx.x * 256 + threadIdx.x;
    if (r > N_NODES) return;
    int lo = 0, hi = NNZ_E;
    while (lo < hi) {
        int mid = (lo + hi) >> 1;
        if (rows[mid] < r) lo = mid + 1; else hi = mid;
    }
    row_ptr[r] = lo;
}

// ---------------------------------------------------------------------------
// K2: XW = x_q @ w1q  (fp8 MFMA 16x16x32, fp32 acc) -> xw fp8 [N,256]
// m97-style: 128x128 block tile, BK=64, global_load_lds(16B) staging,
// XOR-swizzled LDS (8B-chunk index ^= row&6) -> 2-way bank alias (free).
// 4 waves: (wv&1)=M-half, (wv>>1)=N-half, each 64x64 as 4x4 of 16x16.
// Grid: (782, 2).
// ---------------------------------------------------------------------------
__global__ __launch_bounds__(256) void gemm1_kernel(const unsigned char* __restrict__ xq,
                                                    const unsigned char* __restrict__ w1q,
                                                    unsigned char* __restrict__ xw) {
    __shared__ unsigned char As[8192];   // 128 rows x 64 B (swizzled)
    __shared__ unsigned char Bs[8192];   // 128 n    x 64 B (swizzled)

    const int wv   = threadIdx.x >> 6;
    const int lane = threadIdx.x & 63;
    const int l15  = lane & 15;
    const int quad = lane >> 4;
    const int rb   = blockIdx.x * 128;
    const int nb   = blockIdx.y * 128;

    // staging lane coords (constant across kc)
    const int srow0 = (wv * 2 + 0) * 16 + (lane >> 2);   // load 0 local row
    const int srow1 = (wv * 2 + 1) * 16 + (lane >> 2);   // load 1 local row
    const int g0 = (lane & 3) ^ ((srow0 >> 1) & 3);      // swizzled 16B chunk
    const int g1 = (lane & 3) ^ ((srow1 >> 1) & 3);
    int ga0 = rb + srow0; if (ga0 >= N_NODES) ga0 = N_NODES - 1;
    int ga1 = rb + srow1; if (ga1 >= N_NODES) ga1 = N_NODES - 1;
    const unsigned char* agp0 = xq + (long)ga0 * NFEAT + g0 * 16;
    const unsigned char* agp1 = xq + (long)ga1 * NFEAT + g1 * 16;
    const unsigned char* bgp0 = w1q + (long)(nb + srow0) * NFEAT + g0 * 16;
    const unsigned char* bgp1 = w1q + (long)(nb + srow1) * NFEAT + g1 * 16;

    f32x4 acc[4][4] = {};

    for (int kc = 0; kc < NFEAT; kc += 64) {
        __builtin_amdgcn_global_load_lds((gu32*)(agp0 + kc), (lu32*)(As + (wv * 2 + 0) * 1024), 16, 0, 0);
        __builtin_amdgcn_global_load_lds((gu32*)(agp1 + kc), (lu32*)(As + (wv * 2 + 1) * 1024), 16, 0, 0);
        __builtin_amdgcn_global_load_lds((gu32*)(bgp0 + kc), (lu32*)(Bs + (wv * 2 + 0) * 1024), 16, 0, 0);
        __builtin_amdgcn_global_load_lds((gu32*)(bgp1 + kc), (lu32*)(Bs + (wv * 2 + 1) * 1024), 16, 0, 0);
        __syncthreads();

        unsigned long long a[4][2], b[4][2];
#pragma unroll
        for (int mt = 0; mt < 4; mt++) {
            int row = (wv & 1) * 64 + mt * 16 + l15;
#pragma unroll
            for (int ks = 0; ks < 2; ks++) {
                int p8 = (ks * 4 + quad) ^ (row & 6);
                a[mt][ks] = *(const unsigned long long*)(As + row * 64 + p8 * 8);
            }
        }
#pragma unroll
        for (int nt = 0; nt < 4; nt++) {
            int nr = (wv >> 1) * 64 + nt * 16 + l15;
#pragma unroll
            for (int ks = 0; ks < 2; ks++) {
                int p8 = (ks * 4 + quad) ^ (nr & 6);
                b[nt][ks] = *(const unsigned long long*)(Bs + nr * 64 + p8 * 8);
            }
        }
#pragma unroll
        for (int ks = 0; ks < 2; ks++)
#pragma unroll
            for (int nt = 0; nt < 4; nt++)
#pragma unroll
                for (int mt = 0; mt < 4; mt++)
                    acc[mt][nt] = __builtin_amdgcn_mfma_f32_16x16x32_fp8_fp8(
                        (long)a[mt][ks], (long)b[nt][ks], acc[mt][nt], 0, 0, 0);
        __syncthreads();
    }

    // epilogue: C/D layout col=lane&15, row=quad*4+reg
#pragma unroll
    for (int mt = 0; mt < 4; mt++) {
        int row0 = rb + (wv & 1) * 64 + mt * 16 + quad * 4;
#pragma unroll
        for (int nt = 0; nt < 4; nt++) {
            int col = nb + (wv >> 1) * 64 + nt * 16 + l15;
#pragma unroll
            for (int r = 0; r < 4; r++) {
                int row = row0 + r;
                if (row < N_NODES)
                    xw[(long)row * NHID + col] = f2fp8(acc[mt][nt][r]);
            }
        }
    }
}

// ---------------------------------------------------------------------------
// K3: h = relu(spmm(A, xw) + b1) -> bf16 [N,256].  One wave per row.
// xw is fp8: lane covers cols 4*lane..4*lane+3, one uint gather per edge.
// ---------------------------------------------------------------------------
__global__ __launch_bounds__(256) void spmm1_kernel(const unsigned char* __restrict__ xw,
                                                    const int* __restrict__ row_ptr,
                                                    const int* __restrict__ cols,
                                                    const float* __restrict__ vals,
                                                    const float* __restrict__ b1,
                                                    unsigned short* __restrict__ h) {
    int row = blockIdx.x * 4 + (threadIdx.x >> 6);
    if (row >= N_NODES) return;
    int lane = threadIdx.x & 63;
    int e0 = row_ptr[row], e1 = row_ptr[row + 1];

    float a0 = 0.f, a1 = 0.f, a2 = 0.f, a3 = 0.f;
    for (int base = e0; base < e1; base += 64) {
        int   myc = 0;
        float myv = 0.f;
        int idx = base + lane;
        if (idx < e1) { myc = cols[idx]; myv = vals[idx]; }
        int cnt = e1 - base; if (cnt > 64) cnt = 64;
        int j = 0;
        for (; j + 8 <= cnt; j += 8) {
            int c[8]; float v[8];
#pragma unroll
            for (int u = 0; u < 8; u++) { c[u] = __shfl(myc, j + u); v[u] = __shfl(myv, j + u); }
            unsigned q[8];
#pragma unroll
            for (int u = 0; u < 8; u++) q[u] = *(const unsigned*)(xw + (long)c[u] * NHID + lane * 4);
#pragma unroll
            for (int u = 0; u < 8; u++) {
                f32x2 lo = __builtin_amdgcn_cvt_pk_f32_fp8((int)q[u], false);
                f32x2 hi = __builtin_amdgcn_cvt_pk_f32_fp8((int)q[u], true);
                a0 += v[u] * lo[0];
                a1 += v[u] * lo[1];
                a2 += v[u] * hi[0];
                a3 += v[u] * hi[1];
            }
        }
        for (; j < cnt; j++) {
            int   c = __shfl(myc, j);
            float v = __shfl(myv, j);
            unsigned q = *(const unsigned*)(xw + (long)c * NHID + lane * 4);
            f32x2 lo = __builtin_amdgcn_cvt_pk_f32_fp8((int)q, false);
            f32x2 hi = __builtin_amdgcn_cvt_pk_f32_fp8((int)q, true);
            a0 += v * lo[0];
            a1 += v * lo[1];
            a2 += v * hi[0];
            a3 += v * hi[1];
        }
    }
    float4 bv = *(const float4*)(b1 + lane * 4);
    a0 = fmaxf(a0 + bv.x, 0.f);
    a1 = fmaxf(a1 + bv.y, 0.f);
    a2 = fmaxf(a2 + bv.z, 0.f);
    a3 = fmaxf(a3 + bv.w, 0.f);
    uint2 o;
    o.x = (unsigned)f2bf(a0) | ((unsigned)f2bf(a1) << 16);
    o.y = (unsigned)f2bf(a2) | ((unsigned)f2bf(a3) << 16);
    *(uint2*)(h + (long)row * NHID + lane * 4) = o;
}

// ---------------------------------------------------------------------------
// K4: p = h @ w2  (bf16 MFMA) -> fp8 [N, P_STRIDE=64] (cols 0..47 written)
// ---------------------------------------------------------------------------
__global__ __launch_bounds__(256) void gemm2_kernel(const unsigned short* __restrict__ h,
                                                    const unsigned short* __restrict__ w2t,
                                                    unsigned char* __restrict__ p) {
    int rt = blockIdx.x * 4 + (threadIdx.x >> 6);
    int row0 = rt * 16;
    if (row0 >= N_NODES) return;
    int lane = threadIdx.x & 63;
    int l15 = lane & 15, quad = lane >> 4;

    int arow = row0 + l15; if (arow >= N_NODES) arow = N_NODES - 1;
    f32x4 acc[3] = {};
#pragma unroll
    for (int kc = 0; kc < NHID; kc += 32) {
        short8 a = *(const short8*)(h + (long)arow * NHID + kc + quad * 8);
#pragma unroll
        for (int nt = 0; nt < 3; nt++) {
            short8 b = *(const short8*)(w2t + (long)(nt * 16 + l15) * NHID + kc + quad * 8);
            acc[nt] = __builtin_amdgcn_mfma_f32_16x16x32_bf16(a, b, acc[nt], 0, 0, 0);
        }
    }
#pragma unroll
    for (int nt = 0; nt < 3; nt++) {
        int col = nt * 16 + l15;
#pragma unroll
        for (int r = 0; r < 4; r++) {
            int row = row0 + quad * 4 + r;
            if (row < N_NODES)
                p[(long)row * P_STRIDE + col] = f2fp8(acc[nt][r]);
        }
    }
}

// ---------------------------------------------------------------------------
// K5: out = log_softmax(spmm(A, p) + b2).  One wave per row.
// p is fp8, 64 B rows. e = lane>>5 (edge of pair), t = lane&31;
// t<12 loads uint = cols {4t..4t+3}. 2 edges/j-step, unroll 4.
// ---------------------------------------------------------------------------
__global__ __launch_bounds__(256) void spmm2_kernel(const unsigned char* __restrict__ p,
                                                    const int* __restrict__ row_ptr,
                                                    const int* __restrict__ cols,
                                                    const float* __restrict__ vals,
                                                    const float* __restrict__ b2,
                                                    float* __restrict__ out) {
    int row = blockIdx.x * 4 + (threadIdx.x >> 6);
    if (row >= N_NODES) return;
    int lane = threadIdx.x & 63;
    int e = lane >> 5;
    int t = lane & 31;
    int e0 = row_ptr[row], e1 = row_ptr[row + 1];

    float a0 = 0.f, a1 = 0.f, a2 = 0.f, a3 = 0.f;
    for (int base = e0; base < e1; base += 64) {
        int   myc = 0;
        float myv = 0.f;
        int idx = base + lane;
        if (idx < e1) { myc = cols[idx]; myv = vals[idx]; }
        int cnt = e1 - base; if (cnt > 64) cnt = 64;
        int j = 0;
        for (; j + 8 <= cnt; j += 8) {
            int c[4]; float v[4];
#pragma unroll
            for (int u = 0; u < 4; u++) {
                c[u] = __shfl(myc, j + 2 * u + e);
                v[u] = __shfl(myv, j + 2 * u + e);
            }
            unsigned q[4];
#pragma unroll
            for (int u = 0; u < 4; u++)
                q[u] = (t < 12) ? *(const unsigned*)(p + (long)c[u] * P_STRIDE + 4 * t) : 0u;
#pragma unroll
            for (int u = 0; u < 4; u++) {
                f32x2 lo = __builtin_amdgcn_cvt_pk_f32_fp8((int)q[u], false);
                f32x2 hi = __builtin_amdgcn_cvt_pk_f32_fp8((int)q[u], true);
                a0 += v[u] * lo[0];
                a1 += v[u] * lo[1];
                a2 += v[u] * hi[0];
                a3 += v[u] * hi[1];
            }
        }
        for (; j < cnt; j += 2) {
            int jj = j + e;
            int jc = jj < cnt ? jj : cnt - 1;       // uniform-exec tail
            int   c = __shfl(myc, jc);
            float v = __shfl(myv, jc);
            if (jj >= cnt) v = 0.f;
            unsigned q = (t < 12) ? *(const unsigned*)(p + (long)c * P_STRIDE + 4 * t) : 0u;
            f32x2 lo = __builtin_amdgcn_cvt_pk_f32_fp8((int)q, false);
            f32x2 hi = __builtin_amdgcn_cvt_pk_f32_fp8((int)q, true);
            a0 += v * lo[0];
            a1 += v * lo[1];
            a2 += v * hi[0];
            a3 += v * hi[1];
        }
    }
    // fold the two edge-halves
    a0 += __shfl_xor(a0, 32);
    a1 += __shfl_xor(a1, 32);
    a2 += __shfl_xor(a2, 32);
    a3 += __shfl_xor(a3, 32);

    int c0 = 4 * t, c1 = 4 * t + 1, c2 = 4 * t + 2, c3 = 4 * t + 3;
    float l0 = (c0 < NCLASS) ? a0 + b2[c0] : -__builtin_inff();
    float l1 = (c1 < NCLASS) ? a1 + b2[c1] : -__builtin_inff();
    float l2 = (c2 < NCLASS) ? a2 + b2[c2] : -__builtin_inff();
    float l3 = (c3 < NCLASS) ? a3 + b2[c3] : -__builtin_inff();
    float m = fmaxf(fmaxf(l0, l1), fmaxf(l2, l3));
#pragma unroll
    for (int s = 16; s; s >>= 1) m = fmaxf(m, __shfl_xor(m, s));
    float esum = ((c0 < NCLASS) ? __expf(l0 - m) : 0.f)
               + ((c1 < NCLASS) ? __expf(l1 - m) : 0.f)
               + ((c2 < NCLASS) ? __expf(l2 - m) : 0.f)
               + ((c3 < NCLASS) ? __expf(l3 - m) : 0.f);
#pragma unroll
    for (int s = 16; s; s >>= 1) esum += __shfl_xor(esum, s);
    float lse = m + __logf(esum);
    if (e == 0) {
        long ob = (long)row * NCLASS;
        if (c0 < NCLASS) out[ob + c0] = l0 - lse;
        if (c1 < NCLASS) out[ob + c1] = l1 - lse;
        if (c2 < NCLASS) out[ob + c2] = l2 - lse;
        if (c3 < NCLASS) out[ob + c3] = l3 - lse;
    }
}

// ---------------------------------------------------------------------------
extern "C" void kernel_launch(void* const* d_in, const int* in_sizes, int n_in,
                              void* d_out, int out_size, void* d_ws, size_t ws_size,
                              hipStream_t stream) {
    const float* x        = (const float*)d_in[0];
    const int*   adj_rows = (const int*)  d_in[1];
    const int*   adj_cols = (const int*)  d_in[2];
    const float* adj_vals = (const float*)d_in[3];
    const float* w1       = (const float*)d_in[4];
    const float* b1       = (const float*)d_in[5];
    const float* w2       = (const float*)d_in[6];
    const float* b2       = (const float*)d_in[7];
    float* out = (float*)d_out;

    // workspace layout (aliased by liveness):
    //   region1 (51.2 MB): x_q (prep->gemm1)  then hbuf (spmm1->gemm2)
    //   region2 (25.6 MB): xw  (gemm1->spmm1) then p    (gemm2->spmm2)
    char* ws = (char*)d_ws;
    unsigned char*  w1q     = (unsigned char*) (ws);                  // 128 KB
    unsigned short* w2t     = (unsigned short*)(ws + 0x20000);        // 24 KB
    int*            row_ptr = (int*)           (ws + 0x26000);        // 0.4 MB
    unsigned char*  xq      = (unsigned char*) (ws + 0x90000);        // 51.2 MB fp8 [N,512]
    unsigned short* hbuf    = (unsigned short*)(ws + 0x90000);        // 51.2 MB bf16 [N,256] (aliases xq)
    unsigned char*  xw      = (unsigned char*) (ws + 0x3180000);      // 25.6 MB fp8 [N,256]
    unsigned char*  p       = (unsigned char*) (ws + 0x3180000);      // 6.4 MB fp8 [N,64] (aliases xw)

    prep_x_kernel<<<(N_NODES * NFEAT) / 16 / 256, 256, 0, stream>>>(x, xq);
    prep_w_kernel<<<(NHID * NFEAT + NC_PAD * NHID + 255) / 256, 256, 0, stream>>>(w1, w2, w1q, w2t);
    rowptr_kernel<<<(N_NODES + 1 + 255) / 256, 256, 0, stream>>>(adj_rows, row_ptr);
    gemm1_kernel<<<dim3((N_NODES + 127) / 128, 2), 256, 0, stream>>>(xq, w1q, xw);
    spmm1_kernel<<<(N_NODES + 3) / 4, 256, 0, stream>>>(xw, row_ptr, adj_cols, adj_vals, b1, hbuf);
    gemm2_kernel<<<((N_NODES + 15) / 16 + 3) / 4, 256, 0, stream>>>(hbuf, w2t, p);
    spmm2_kernel<<<(N_NODES + 3) / 4, 256, 0, stream>>>(p, row_ptr, adj_cols, adj_vals, b2, out);
}